// Round 12
// baseline (188.913 us; speedup 1.0000x reference)
//
#include <hip/hip_runtime.h>
#include <hip/hip_bf16.h>
#include <math.h>

// Problem constants (B=8, C=256, H=W=64, WS=8, NH=8)
// DTYPES: all inputs fp32, output fp32 (harness compares in bf16 space).
// r12 structural change: x is read ONCE. The SE gate (a k-axis diagonal) is
// folded into per-batch weight copies instead of the activation:
//   QKV[m][n] = sum_c bf16(x)[m][c] * bf16(ipw[n][c]*ca[b(m)][c]*alpha_sec)
// k_perm: x -> Abu (ungated bf16, window-permuted) + per-(b,c,hw) partial sums
//   (each slot written once; no atomics, no zeroing of poisoned ws).
// k_wcvt: each block redundantly computes ca[b] from partials (r8 trick), then
//   converts its slice of Wqb8[b][768][256]; +32 blocks convert Wob; block
//   lb==0 of each b publishes ca for out3's residual.
// out3 residual = Abu[mres]*ca (output quirk: H=window idx, W=pixel):
//   mres = ((hw*8+(px>>3))*8+b)*64 + ww*8+(px&7), hw=w_idx>>3, ww=w_idx&7.
// Attn: ALPHA fold (exp2 softmax), ones-MFMA denominator (r10).
// GEMM ledger: source dbuf defeated by vmcnt(0) (r4); acc[4][8] VGPR blowup
// (r5-r8); out3-geometry 64mx128n acc[2][4] proven (r9); qkv dual 64-k buffer,
// one drain/128k, 3 blocks/CU (r11).
// ws layout: Q @0, K @16M, V @32M; small @48M: ca +0(8K), partials +8K(64K),
// Wob +128K(128K), Wqb8 +1M(3.15M), Abu +8M(16M). big_ws needs >= 72M.
// Fallback (ws small): Abu @ d_out, Wqb8 @ d_out+16M, Wob=Vb post-attn cvt,
// out3 residual via x*ca (G=nullptr).

typedef unsigned short ushort_t;
typedef unsigned int uint_t;
typedef __attribute__((ext_vector_type(8))) short bf16x8;
typedef __attribute__((ext_vector_type(4))) float f32x4;

#define ALPHA 0.25503486f   // log2(e) / sqrt(32)

__device__ __forceinline__ uint_t pk_rne(float a, float b) {     // bf16 pack, RNE
    __hip_bfloat16 ha = __float2bfloat16(a), hb = __float2bfloat16(b);
    ushort_t ua = *(ushort_t*)&ha, ub = *(ushort_t*)&hb;
    return (uint_t)ua | ((uint_t)ub << 16);
}

// bf16 pack (truncate) via single v_perm_b32: low16 = hi(a), high16 = hi(b)
__device__ __forceinline__ uint_t pk2(float a, float b) {
    union { float f; uint_t u; } ua, ub; ua.f = a; ub.f = b;
    return __builtin_amdgcn_perm(ua.u, ub.u, 0x03020706u);
}

__device__ __forceinline__ float bfh(uint_t h) {                 // bf16 bits -> f32
    union { uint_t u; float f; } t; t.u = h << 16; return t.f;
}

// async global->LDS 16B: LDS dest must be wave-uniform base (+lane*16 implicit)
__device__ __forceinline__ void gl_lds16(const ushort_t* g, ushort_t* l) {
    __builtin_amdgcn_global_load_lds(
        (__attribute__((address_space(1))) unsigned int*)(g),
        (__attribute__((address_space(3))) unsigned int*)(l), 16, 0, 0);
}

// ------- Kernel 1b (fallback only): fp32 -> bf16 weight convert --------------
__global__ __launch_bounds__(256) void k_cvt(const float* __restrict__ src,
                                             ushort_t* __restrict__ dst, int n8,
                                             int scale_n8, float scale) {
    int i = blockIdx.x * 256 + threadIdx.x;
    if (i >= n8) return;
    float sc = (i < scale_n8) ? scale : 1.f;
    const float4* s = (const float4*)src + (size_t)i * 2;
    float4 a = s[0], b = s[1];
    uint4 u;
    u.x = pk_rne(a.x * sc, a.y * sc); u.y = pk_rne(a.z * sc, a.w * sc);
    u.z = pk_rne(b.x * sc, b.y * sc); u.w = pk_rne(b.z * sc, b.w * sc);
    *(uint4*)(dst + (size_t)i * 8) = u;
}

// --- Kernel 1: single-pass x -> Abu (ungated bf16, permuted) + pool partials -
// Block (b, hw, c0): thread t owns channel ch=t>>3, slice s=t&7 (16 float4).
// Partial channel sums reduced 8-way in LDS -> partials[(b*256+c)*8+hw].
#define GPAD 524
__global__ __launch_bounds__(256) void k_perm(const float* __restrict__ x,
                                              ushort_t* __restrict__ Abu,
                                              float* __restrict__ partials) {
    __shared__ __align__(16) ushort_t Ls[32 * GPAD];
    __shared__ float sred[256];
    int bx = blockIdx.x;
    int b = bx >> 6, hw = (bx >> 3) & 7, c0 = (bx & 7) * 32;
    int t = threadIdx.x;
    int ch = t >> 3, s = t & 7;
    const float4* xc = (const float4*)(x + ((size_t)(b * 256 + c0 + ch) * 64 + hw * 8) * 64);
    float psum = 0.f;
#pragma unroll
    for (int j = 0; j < 16; j++) {
        int u = j * 8 + s;                 // 0..127 = r*16+w4
        float4 v = xc[u];
        psum += (v.x + v.y) + (v.z + v.w);
        uint2 uu;
        uu.x = pk_rne(v.x, v.y);
        uu.y = pk_rne(v.z, v.w);
        *(uint2*)&Ls[ch * GPAD + u * 4] = uu;
    }
    sred[t] = psum;
    __syncthreads();
    if (s < 4) sred[t] += sred[t + 4];
    __syncthreads();
    if (s < 2) sred[t] += sred[t + 2];
    __syncthreads();
    if (s == 0) partials[((size_t)(b * 256 + c0 + ch)) * 8 + hw] = sred[t] + sred[t + 1];
    __syncthreads();
    // phase 2: permuted write-out (unchanged layout)
#pragma unroll
    for (int i = 0; i < 8; i++) {
        int q = i * 256 + t;
        int rr = q >> 2, part = q & 3;
        int ww = rr >> 6, p = rr & 63;
        int px = (p >> 3) * 64 + ww * 8 + (p & 7);
        const ushort_t* ls = &Ls[part * 8 * GPAD + px];
        uint4 u;
        u.x = (uint_t)ls[0]        | ((uint_t)ls[GPAD] << 16);
        u.y = (uint_t)ls[2 * GPAD] | ((uint_t)ls[3 * GPAD] << 16);
        u.z = (uint_t)ls[4 * GPAD] | ((uint_t)ls[5 * GPAD] << 16);
        u.w = (uint_t)ls[6 * GPAD] | ((uint_t)ls[7 * GPAD] << 16);
        size_t m = (size_t)(((hw * 8 + ww) * 8 + b) * 64 + p);
        *(uint4*)(Abu + m * 256 + c0 + part * 8) = u;
    }
}

// --- Kernel 2: inline-SE + per-batch gated weight convert --------------------
// Blocks 0..767: (b = bx/96, lb = bx%96). Redundantly compute ca[b] from
// partials (pooled exact fp32), then convert 256 groups-of-8 of
// Wqb8[b][n][c] = bf16(ipw[n][c] * ca[b][c] * (ALPHA if n<256)).
// lb==0 publishes ca[b] for out3. Blocks 768..799 (big_ws): Wob convert.
__global__ __launch_bounds__(256) void k_wcvt(const float* __restrict__ ipw,
                                              const float* __restrict__ w1,
                                              const float* __restrict__ b1,
                                              const float* __restrict__ w2,
                                              const float* __restrict__ b2,
                                              const float* __restrict__ partials,
                                              ushort_t* __restrict__ Wqb8,
                                              float* __restrict__ ca_out,
                                              const float* __restrict__ opw,
                                              ushort_t* __restrict__ Wob) {
    int bx = blockIdx.x;
    int t = threadIdx.x;
    if (bx < 768) {
        __shared__ float sp[256];
        __shared__ float sh1[64];
        __shared__ float sca[256];
        int b = bx / 96, lb = bx - b * 96;
        {   // pooled[b][t] from 8 hw-partials (deterministic fp32)
            const float* pp = partials + ((size_t)(b * 256 + t)) * 8;
            float s = ((pp[0] + pp[1]) + (pp[2] + pp[3])) + ((pp[4] + pp[5]) + (pp[6] + pp[7]));
            sp[t] = s * (1.f / 4096.f);
        }
        __syncthreads();
        if (t < 64) {                      // h1 = relu(pooled @ w1^T + b1)
            float s = b1[t];
            const float* wr = w1 + (size_t)t * 256;
            for (int c = 0; c < 256; c++) s += sp[c] * wr[c];
            sh1[t] = s > 0.f ? s : 0.f;
        }
        __syncthreads();
        {   // ca[t] = sigmoid(h1 @ w2[t]^T + b2)
            float s = b2[t];
            const float* wr = w2 + (size_t)t * 64;
            for (int j = 0; j < 64; j++) s += sh1[j] * wr[j];
            sca[t] = 1.f / (1.f + __expf(-s));
        }
        __syncthreads();
        if (lb == 0) ca_out[b * 256 + t] = sca[t];
        int i = lb * 256 + t;              // group idx 0..24575
        int n = i >> 5, c0g = (i & 31) * 8;
        float asec = (n < 256) ? ALPHA : 1.f;
        const float4* s4 = (const float4*)(ipw + (size_t)n * 256 + c0g);
        float4 a = s4[0], bb = s4[1];
        uint4 u;
        u.x = pk_rne(a.x * sca[c0g] * asec,      a.y * sca[c0g + 1] * asec);
        u.y = pk_rne(a.z * sca[c0g + 2] * asec,  a.w * sca[c0g + 3] * asec);
        u.z = pk_rne(bb.x * sca[c0g + 4] * asec, bb.y * sca[c0g + 5] * asec);
        u.w = pk_rne(bb.z * sca[c0g + 6] * asec, bb.w * sca[c0g + 7] * asec);
        *(uint4*)(Wqb8 + ((size_t)b * 24576 + i) * 8) = u;
    } else {
        int i = (bx - 768) * 256 + t;      // 0..8191
        const float4* s4 = (const float4*)opw + (size_t)i * 2;
        float4 a = s4[0], b = s4[1];
        uint4 u;
        u.x = pk_rne(a.x, a.y); u.y = pk_rne(a.z, a.w);
        u.z = pk_rne(b.x, b.y); u.w = pk_rne(b.z, b.w);
        *(uint4*)(Wob + (size_t)i * 8) = u;
    }
}

// ------- Kernel 3: QKV GEMM, 64m x 128n, dual 64-k buffers, one drain/128k ---
// B = Wqb8[b] (gate folded into weights); b = mi&7 (token & 7). 3 blocks/CU.
__global__ __launch_bounds__(256, 3) void k_gemm_qkv4(const ushort_t* __restrict__ A,
                                                      const ushort_t* __restrict__ Bw,
                                                      const float* __restrict__ bias,
                                                      ushort_t* __restrict__ Qb,
                                                      ushort_t* __restrict__ Kb,
                                                      ushort_t* __restrict__ Vb) {
    __shared__ __align__(16) ushort_t As[2][4096];   // 2 x 8 KiB
    __shared__ __align__(16) ushort_t Bs[2][8192];   // 2 x 16 KiB
    int tid = threadIdx.x;
    int lane = tid & 63, wave = tid >> 6;
    int wm = wave >> 1, wn = wave & 1;             // wave tile: 32m x 64n
    int col = lane & 15, quad = lane >> 4;
    int orig = blockIdx.x;                // 0..3071
    int xcd = orig & 7;
    int i384 = orig >> 3;                 // 0..383
    int mi = i384 / 6;                    // 0..63 local m-panel
    int r6 = i384 - mi * 6;               // 0..5
    int sec = r6 >> 1, nh = r6 & 1;
    int m0 = (xcd * 64 + mi) * 64;
    int b = mi & 7;                       // token & 7 (xcd*64 == 0 mod 8)
    const ushort_t* Bsec = Bw + (size_t)b * 196608 + ((size_t)sec << 16) + ((size_t)nh * 128) * 256;

    int cbase = wave * 64 + lane;
    const ushort_t* asrc[2];
    const ushort_t* bsrc[4];
#pragma unroll
    for (int q = 0; q < 2; q++) {
        int c = q * 256 + cbase;          // A chunk 0..511
        int row = c >> 3;                 // 0..63
        int kp = (c & 7) ^ (row & 7);     // pre-swizzled source k-part
        asrc[q] = A + (size_t)(m0 + row) * 256 + kp * 8;
    }
#pragma unroll
    for (int q = 0; q < 4; q++) {
        int c = q * 256 + cbase;          // B chunk 0..1023
        int row = c >> 3;                 // 0..127
        int kp = (c & 7) ^ (row & 7);
        bsrc[q] = Bsec + (size_t)row * 256 + kp * 8;
    }

    f32x4 acc[2][4];
#pragma unroll
    for (int i = 0; i < 2; i++)
#pragma unroll
        for (int j = 0; j < 4; j++) acc[i][j] = (f32x4){0.f, 0.f, 0.f, 0.f};

    for (int t2 = 0; t2 < 2; t2++) {
        int k0 = t2 * 128;
#pragma unroll
        for (int h = 0; h < 2; h++) {     // two 64-k halves, back-to-back issue
#pragma unroll
            for (int q = 0; q < 2; q++)
                gl_lds16(asrc[q] + k0 + h * 64, &As[h][(q * 4 + wave) * 512]);
#pragma unroll
            for (int q = 0; q < 4; q++)
                gl_lds16(bsrc[q] + k0 + h * 64, &Bs[h][(q * 4 + wave) * 512]);
        }
        __syncthreads();                  // single drain covers 128 k
#pragma unroll
        for (int h = 0; h < 2; h++) {
            const ushort_t* Ac = As[h];
            const ushort_t* Bc = Bs[h];
#pragma unroll
            for (int kk = 0; kk < 2; kk++) {
                bf16x8 af[2], bfg[4];
#pragma unroll
                for (int i = 0; i < 2; i++) {
                    int row = wm * 32 + i * 16 + col;
                    af[i] = *(const bf16x8*)&Ac[row * 64 + ((kk * 4 + quad) ^ (row & 7)) * 8];
                }
#pragma unroll
                for (int j = 0; j < 4; j++) {
                    int row = wn * 64 + j * 16 + col;
                    bfg[j] = *(const bf16x8*)&Bc[row * 64 + ((kk * 4 + quad) ^ (row & 7)) * 8];
                }
#pragma unroll
                for (int i = 0; i < 2; i++)
#pragma unroll
                    for (int j = 0; j < 4; j++)
                        acc[i][j] = __builtin_amdgcn_mfma_f32_16x16x32_bf16(bfg[j], af[i], acc[i][j], 0, 0, 0);
            }
        }
        __syncthreads();
    }

    // epilogue: n_sec = nh*128 + wn*64 + j*16 + quad*4 + r; m = m0+wm*32+i*16+col
    ushort_t* dst = (sec == 0) ? Qb : (sec == 1) ? Kb : Vb;
    float bsc = (sec == 0) ? ALPHA : 1.f;    // Q bias folded with softmax scale
    int nb0 = nh * 128 + wn * 64 + quad * 4;
#pragma unroll
    for (int j = 0; j < 4; j++) {
        float4 bv = *(const float4*)(bias + sec * 256 + nb0 + j * 16);
        bv.x *= bsc; bv.y *= bsc; bv.z *= bsc; bv.w *= bsc;
#pragma unroll
        for (int i = 0; i < 2; i++) {
            int m = m0 + wm * 32 + i * 16 + col;
            uint2 st;
            st.x = pk_rne(acc[i][j][0] + bv.x, acc[i][j][1] + bv.y);
            st.y = pk_rne(acc[i][j][2] + bv.z, acc[i][j][3] + bv.w);
            *(uint2*)(dst + (size_t)m * 256 + nb0 + j * 16) = st;
        }
    }
}

// ---------------- Kernel 4: MFMA attention per (pixel p, head h) ----------------
// 512 threads (8 waves, 4 q-tiles each), single-shot staging of all 512 keys.
// Ks[key][32] with chunk XOR (quad ^ (key>>3)&3): conflict-free b128 reads.
// Vt[vc][512] transposed; swizzle swz(vc) = (vc&7) ^ ((vc>>3)<<1) on write AND read.
// Q pre-scaled by ALPHA (log2 domain) -> softmax numerator is bare v_exp_f32.
// qsum via ones-operand MFMA (accS) — row-sum on the matrix pipe (r10).
__global__ __launch_bounds__(512, 4) void k_attn(const ushort_t* __restrict__ Qb,
                                                 const ushort_t* __restrict__ Kb,
                                                 const ushort_t* __restrict__ Vb,
                                                 ushort_t* __restrict__ AO) {
    __shared__ __align__(16) ushort_t Ks[512 * 32];   // 32 KiB
    __shared__ __align__(16) ushort_t Vt[32 * 512];   // 32 KiB
    int p = blockIdx.x >> 3, h = blockIdx.x & 7;
    int tid = threadIdx.x;
    int lane = tid & 63, wave = tid >> 6;             // wave 0..7
    int col = lane & 15, quad = lane >> 4;

    // K staging: unit = (key, oct); bf16x8 -> swizzled chunk
#pragma unroll
    for (int it = 0; it < 4; it++) {
        int u = it * 512 + tid;
        int key = u >> 2, oct = u & 3;
        size_t grow = ((size_t)(key * 64 + p)) * 256 + h * 32 + oct * 8;
        int ck = oct ^ ((key >> 3) & 3);
        *(bf16x8*)&Ks[key * 32 + ck * 8] = *(const bf16x8*)(Kb + grow);
    }
    // V staging: unit = (key-pair, oct); pack 2 keys/chan -> ds_write_b32
#pragma unroll
    for (int it = 0; it < 2; it++) {
        int u = it * 512 + tid;
        int kp = u >> 2, oct = u & 3;
        int k0 = kp * 2;
        size_t g0 = ((size_t)(k0 * 64 + p)) * 256 + h * 32 + oct * 8;
        bf16x8 v0 = *(const bf16x8*)(Vb + g0);
        bf16x8 v1 = *(const bf16x8*)(Vb + g0 + 16384);   // key+1 row
        int kc = kp >> 2;                                // key>>3
#pragma unroll
        for (int j = 0; j < 8; j++) {
            int vc = oct * 8 + j;
            int kcs = kc ^ (vc & 7) ^ ((vc >> 3) << 1);
            uint_t pkv = (uint_t)(ushort_t)v0[j] | ((uint_t)(ushort_t)v1[j] << 16);
            *(uint_t*)&Vt[vc * 512 + kcs * 8 + (k0 & 7)] = pkv;
        }
    }

    // Q fragments (independent global loads, overlap with staging)
    bf16x8 qfrag[4];
#pragma unroll
    for (int i = 0; i < 4; i++) {
        int qt = wave * 4 + i;
        qfrag[i] = *(const bf16x8*)(Qb + ((size_t)((qt * 16 + col) * 64 + p)) * 256 + h * 32 + quad * 8);
    }

    f32x4 O0[4], O1[4], accS[4];
#pragma unroll
    for (int i = 0; i < 4; i++) {
        O0[i] = (f32x4){0.f, 0.f, 0.f, 0.f};
        O1[i] = (f32x4){0.f, 0.f, 0.f, 0.f};
        accS[i] = (f32x4){0.f, 0.f, 0.f, 0.f};
    }
    const f32x4 zero = {0.f, 0.f, 0.f, 0.f};
    const short OB = (short)0x3F80;                  // bf16 1.0
    const bf16x8 ones8 = {OB, OB, OB, OB, OB, OB, OB, OB};
    int R = col >> 2, r4 = lane & 3;
    int krow0 = 8 * R + r4;                  // kf0 row offset; kf1 = +4
    int vc0 = col, vc1 = col + 16;
    int sw0 = (vc0 & 7) ^ ((vc0 >> 3) << 1); // full swizzle, matches write
    int sw1 = (vc1 & 7) ^ ((vc1 >> 3) << 1);

    __syncthreads();

    for (int c = 0; c < 512; c += 32) {
        int row0 = c + krow0;
        int row1 = row0 + 4;
        int ckq = quad ^ ((row0 >> 3) & 3);  // same for row1 (r4<4)
        bf16x8 kf0 = *(const bf16x8*)&Ks[row0 * 32 + ckq * 8];
        bf16x8 kf1 = *(const bf16x8*)&Ks[row1 * 32 + ckq * 8];
        int kc = (c >> 3) + quad;
        bf16x8 vf0 = *(const bf16x8*)&Vt[vc0 * 512 + ((kc ^ sw0) * 8)];
        bf16x8 vf1 = *(const bf16x8*)&Vt[vc1 * 512 + ((kc ^ sw1) * 8)];
#pragma unroll
        for (int i = 0; i < 4; i++) {
            __builtin_amdgcn_s_setprio(1);
            f32x4 s0 = __builtin_amdgcn_mfma_f32_16x16x32_bf16(kf0, qfrag[i], zero, 0, 0, 0);
            f32x4 s1 = __builtin_amdgcn_mfma_f32_16x16x32_bf16(kf1, qfrag[i], zero, 0, 0, 0);
            __builtin_amdgcn_s_setprio(0);
            float p0[4], p1[4];
#pragma unroll
            for (int r = 0; r < 4; r++) {
                p0[r] = __builtin_amdgcn_exp2f(s0[r]);
                p1[r] = __builtin_amdgcn_exp2f(s1[r]);
            }
            union { uint_t u[4]; bf16x8 v; } pb;
            pb.u[0] = pk2(p0[0], p0[1]);
            pb.u[1] = pk2(p0[2], p0[3]);
            pb.u[2] = pk2(p1[0], p1[1]);
            pb.u[3] = pk2(p1[2], p1[3]);
            __builtin_amdgcn_s_setprio(1);
            O0[i] = __builtin_amdgcn_mfma_f32_16x16x32_bf16(vf0, pb.v, O0[i], 0, 0, 0);
            O1[i] = __builtin_amdgcn_mfma_f32_16x16x32_bf16(vf1, pb.v, O1[i], 0, 0, 0);
            accS[i] = __builtin_amdgcn_mfma_f32_16x16x32_bf16(ones8, pb.v, accS[i], 0, 0, 0);
            __builtin_amdgcn_s_setprio(0);
        }
    }

#pragma unroll
    for (int i = 0; i < 4; i++) {
        float inv = 1.f / accS[i][0];        // full 512-key sum, uniform in quad
        int qt = wave * 4 + i;
        ushort_t* dst = AO + ((size_t)((qt * 16 + col) * 64 + p)) * 256 + h * 32;
        uint2 st0, st1;
        st0.x = pk_rne(O0[i][0] * inv, O0[i][1] * inv);
        st0.y = pk_rne(O0[i][2] * inv, O0[i][3] * inv);
        st1.x = pk_rne(O1[i][0] * inv, O1[i][1] * inv);
        st1.y = pk_rne(O1[i][2] * inv, O1[i][3] * inv);
        *(uint2*)(dst + quad * 4) = st0;
        *(uint2*)(dst + 16 + quad * 4) = st1;
    }
}

// --- Kernel 5: out-proj GEMM + residual + scatter, m97-structure -------------
// Residual (G path): G = Abu (ungated) at re-permuted row mres, times ca[b][n].
__global__ __launch_bounds__(256, 4) void k_gemm_out3(const ushort_t* __restrict__ A,
                                                      const ushort_t* __restrict__ Bw,
                                                      const float* __restrict__ bias,
                                                      const ushort_t* __restrict__ G,
                                                      const float* __restrict__ x,
                                                      const float* __restrict__ ca,
                                                      float* __restrict__ out) {
    __shared__ __align__(16) ushort_t As[4096];    // 8 KiB: 64 rows x 64 k
    __shared__ __align__(16) ushort_t Bs[8192];    // 16 KiB: 128 rows x 64 k
    int tid = threadIdx.x;
    int lane = tid & 63, wave = tid >> 6;
    int wm = wave >> 1, wn = wave & 1;             // wave tile: 32m x 64n
    int col = lane & 15, quad = lane >> 4;
    int orig = blockIdx.x;                // 0..1023
    int xcd = orig & 7;
    int i128 = orig >> 3;                 // 0..127
    int mi = i128 >> 1;                   // 0..63 local m-panel (token)
    int ns = i128 & 1;
    int m0 = (xcd * 64 + mi) * 64;        // token base row
    int n0 = ns * 128;

    int cbase = wave * 64 + lane;
    const ushort_t* asrc[2];
    const ushort_t* bsrc[4];
#pragma unroll
    for (int q = 0; q < 2; q++) {
        int c = q * 256 + cbase;          // A chunk 0..511
        int row = c >> 3;                 // 0..63
        int kp = (c & 7) ^ (row & 7);
        asrc[q] = A + (size_t)(m0 + row) * 256 + kp * 8;
    }
#pragma unroll
    for (int q = 0; q < 4; q++) {
        int c = q * 256 + cbase;          // B chunk 0..1023
        int row = c >> 3;                 // 0..127
        int kp = (c & 7) ^ (row & 7);
        bsrc[q] = Bw + (size_t)(n0 + row) * 256 + kp * 8;
    }

    f32x4 acc[2][4];
#pragma unroll
    for (int i = 0; i < 2; i++)
#pragma unroll
        for (int j = 0; j < 4; j++) acc[i][j] = (f32x4){0.f, 0.f, 0.f, 0.f};

    for (int t = 0; t < 4; t++) {
        int k0 = t * 64;
#pragma unroll
        for (int q = 0; q < 2; q++) gl_lds16(asrc[q] + k0, &As[(q * 4 + wave) * 512]);
#pragma unroll
        for (int q = 0; q < 4; q++) gl_lds16(bsrc[q] + k0, &Bs[(q * 4 + wave) * 512]);
        __syncthreads();
#pragma unroll
        for (int kk = 0; kk < 2; kk++) {
            bf16x8 af[2], bfg[4];
#pragma unroll
            for (int i = 0; i < 2; i++) {
                int row = wm * 32 + i * 16 + col;
                af[i] = *(const bf16x8*)&As[row * 64 + ((kk * 4 + quad) ^ (row & 7)) * 8];
            }
#pragma unroll
            for (int j = 0; j < 4; j++) {
                int row = wn * 64 + j * 16 + col;
                bfg[j] = *(const bf16x8*)&Bs[row * 64 + ((kk * 4 + quad) ^ (row & 7)) * 8];
            }
#pragma unroll
            for (int i = 0; i < 2; i++)
#pragma unroll
                for (int j = 0; j < 4; j++)
                    acc[i][j] = __builtin_amdgcn_mfma_f32_16x16x32_bf16(bfg[j], af[i], acc[i][j], 0, 0, 0);
        }
        __syncthreads();
    }

    // epilogue: block = one token lw = m0>>6; px = wm*32 + i*16 + col
    int lw = m0 >> 6;
    int b = lw & 7, w_idx = lw >> 3;
    int hw = w_idx >> 3, ww = w_idx & 7;
    if (G != nullptr) {
#pragma unroll
        for (int j = 0; j < 4; j++) {
            int nbase = n0 + wn * 64 + j * 16 + quad * 4;
            float4 bv = *(const float4*)(bias + nbase);
            float4 cv = *(const float4*)(ca + b * 256 + nbase);
#pragma unroll
            for (int i = 0; i < 2; i++) {
                int px = wm * 32 + i * 16 + col;
                // residual = bf16(x)[mres] * ca at NORMAL spatial (h=w_idx, w=px)
                int mres = ((hw * 8 + (px >> 3)) * 8 + b) * 64 + ww * 8 + (px & 7);
                uint2 gv = *(const uint2*)(G + (size_t)mres * 256 + nbase);
                float g0 = bfh(gv.x & 0xffffu), g1 = bfh(gv.x >> 16);
                float g2 = bfh(gv.y & 0xffffu), g3 = bfh(gv.y >> 16);
                size_t ob = (((size_t)b * 256 + nbase) * 64 + w_idx) * 64 + px;
                out[ob]            = acc[i][j][0] + bv.x + g0 * cv.x;
                out[ob + 4096]     = acc[i][j][1] + bv.y + g1 * cv.y;
                out[ob + 2 * 4096] = acc[i][j][2] + bv.z + g2 * cv.z;
                out[ob + 3 * 4096] = acc[i][j][3] + bv.w + g3 * cv.w;
            }
        }
    } else {
#pragma unroll
        for (int j = 0; j < 4; j++) {
            int nbase = n0 + wn * 64 + j * 16 + quad * 4;
            float4 bv = *(const float4*)(bias + nbase);
            float4 cv = *(const float4*)(ca + b * 256 + nbase);
#pragma unroll
            for (int i = 0; i < 2; i++) {
                int px = wm * 32 + i * 16 + col;
#pragma unroll
                for (int r = 0; r < 4; r++) {
                    int n = nbase + r;
                    float bias_r = (r == 0) ? bv.x : (r == 1) ? bv.y : (r == 2) ? bv.z : bv.w;
                    float ca_r = (r == 0) ? cv.x : (r == 1) ? cv.y : (r == 2) ? cv.z : cv.w;
                    size_t oi = (((size_t)b * 256 + n) * 64 + w_idx) * 64 + px;
                    out[oi] = acc[i][j][r] + bias_r + x[oi] * ca_r;
                }
            }
        }
    }
}

extern "C" void kernel_launch(void* const* d_in, const int* in_sizes, int n_in,
                              void* d_out, int out_size, void* d_ws, size_t ws_size,
                              hipStream_t stream) {
    const float* x     = (const float*)d_in[0];
    const float* ca_w1 = (const float*)d_in[1];
    const float* ca_b1 = (const float*)d_in[2];
    const float* ca_w2 = (const float*)d_in[3];
    const float* ca_b2 = (const float*)d_in[4];
    const float* ipw   = (const float*)d_in[5];
    const float* ipb   = (const float*)d_in[6];
    const float* opw   = (const float*)d_in[7];
    const float* opb   = (const float*)d_in[8];
    float* out = (float*)d_out;

    char* ws = (char*)d_ws;
    const size_t MB16 = 16777216ull;
    ushort_t* Qb = (ushort_t*)(ws + 0);          // 16 MiB; AO aliases this
    ushort_t* Kb = (ushort_t*)(ws + MB16);       // 16 MiB
    ushort_t* Vb = (ushort_t*)(ws + 2 * MB16);   // 16 MiB
    const size_t SM = 3 * MB16;                  // small-region base
    float* ca       = (float*)(ws + SM);                 // 8 KiB
    float* partials = (float*)(ws + SM + 8192);          // 64 KiB
    ushort_t* WobW  = (ushort_t*)(ws + SM + 131072);     // 128 KiB
    const size_t WQB8_OFF = SM + 1048576;                // 3.15 MiB
    const size_t ABU_OFF  = SM + 8 * 1048576;            // 16 MiB
    bool big_ws = (ws_size >= ABU_OFF + MB16);

    ushort_t *Wqb8, *Abu, *Wob;
    const ushort_t* G;
    if (big_ws) {
        Wqb8 = (ushort_t*)(ws + WQB8_OFF);
        Abu  = (ushort_t*)(ws + ABU_OFF);
        Wob  = WobW;
        G    = Abu;                               // residual from Abu * ca
    } else {
        // fallback: d_out as scratch; Wob = Vb via post-attn cvt; residual x*ca
        Abu  = (ushort_t*)d_out;
        Wqb8 = (ushort_t*)((char*)d_out + MB16);
        Wob  = Vb;
        G    = nullptr;
    }

    k_perm<<<512, 256, 0, stream>>>(x, Abu, partials);
    k_wcvt<<<big_ws ? 800 : 768, 256, 0, stream>>>(ipw, ca_w1, ca_b1, ca_w2, ca_b2,
                                                   partials, Wqb8, ca, opw, WobW);
    k_gemm_qkv4<<<3072, 256, 0, stream>>>(Abu, Wqb8, ipb, Qb, Kb, Vb);
    k_attn<<<512, 512, 0, stream>>>(Qb, Kb, Vb, Qb /* AO aliases Q */);
    if (!big_ws) k_cvt<<<32, 256, 0, stream>>>(opw, Vb, 8192, 0, 1.f);
    k_gemm_out3<<<1024, 256, 0, stream>>>(Qb, Wob, opb, G, x, ca, out);
}

// Round 13
// 187.281 us; speedup vs baseline: 1.0087x; 1.0087x over previous
//
#include <hip/hip_runtime.h>
#include <hip/hip_bf16.h>
#include <math.h>

// Problem constants (B=8, C=256, H=W=64, WS=8, NH=8)
// DTYPES: all inputs fp32, output fp32 (harness compares in bf16 space).
// Base = round-11 kernel (183.2us, best verified). r13 change: k_pre's pool
// blocks ALSO emit xbu = bf16(x) (linear layout, coalesced); k_gate reads xbu
// (16 MB) instead of x (64 MB). xbu aliases Kb (dead before qkv4 overwrites).
// [r12 lesson: single-x-pass via per-batch weight copies REGRESSED +5.7us —
//  worse coalescing + 8x B footprint + redundant-SE cost; reverted.]
// ws layout (fill evidence: ws = 256 MiB; big_ws path used when >= 65 MiB):
//   Q @ 0, K @ 16 MiB (aliases xbu pre-qkv), V @ 32 MiB  (AO aliases Q)
//   pooled @ 48 MiB (8 KiB), ca @ +8 KiB, Wob @ +16 KiB (128 KiB),
//   Wqb @ +160 KiB (384 KiB), Ab @ 49 MiB (16 MiB).
// big_ws: d_out holds ONLY the final output; k_gemm_out3 residual from
// Ab = bf16(bf16(x)*ca) at the re-permuted row (output quirk: H=window idx,
// W=pixel): mres = ((hw*8+(px>>3))*8+b)*64 + ww*8+(px&7), hw=w_idx>>3, ww=w_idx&7.
// SE fusion: k_gate computes its own 32-channel ca slice inline (r8).
// Softmax scale fold: Q-section of in_proj W pre-scaled by ALPHA = log2(e)/sqrt(32).
// Attn: ones-MFMA softmax denominator (r10, -3.4us verified).
// GEMM ledger: source dbuf defeated by vmcnt(0) (r4); acc[4][8] VGPR blowup
// (r5-r8); out3-geometry 64mx128n acc[2][4] lb(256,4) proven (r9, -10.6us);
// qkv dual 64-k buffer, one drain/128k, 3 blocks/CU (r11, -1.1us).

typedef unsigned short ushort_t;
typedef unsigned int uint_t;
typedef __attribute__((ext_vector_type(8))) short bf16x8;
typedef __attribute__((ext_vector_type(4))) float f32x4;

#define ALPHA 0.25503486f   // log2(e) / sqrt(32)

__device__ __forceinline__ uint_t pk_rne(float a, float b) {     // bf16 pack, RNE
    __hip_bfloat16 ha = __float2bfloat16(a), hb = __float2bfloat16(b);
    ushort_t ua = *(ushort_t*)&ha, ub = *(ushort_t*)&hb;
    return (uint_t)ua | ((uint_t)ub << 16);
}

// bf16 pack (truncate) via single v_perm_b32: low16 = hi(a), high16 = hi(b)
__device__ __forceinline__ uint_t pk2(float a, float b) {
    union { float f; uint_t u; } ua, ub; ua.f = a; ub.f = b;
    return __builtin_amdgcn_perm(ua.u, ub.u, 0x03020706u);
}

__device__ __forceinline__ float bfh(uint_t h) {                 // bf16 bits -> f32
    union { uint_t u; float f; } t; t.u = h << 16; return t.f;
}

// async global->LDS 16B: LDS dest must be wave-uniform base (+lane*16 implicit)
__device__ __forceinline__ void gl_lds16(const ushort_t* g, ushort_t* l) {
    __builtin_amdgcn_global_load_lds(
        (__attribute__((address_space(1))) unsigned int*)(g),
        (__attribute__((address_space(3))) unsigned int*)(l), 16, 0, 0);
}

// ------ Kernel 0: fused pre-pass. blocks 0..2047: avg-pool row bc=bx AND emit
//        xbu = bf16(x) (linear, coalesced — k_gate re-reads 16MB not 64MB).
//        blocks 2048..2143: in_proj W fp32->bf16 (Q rows scaled by ALPHA).
//        blocks 2144..2175 (big_ws): out_proj W fp32->bf16. -------------------
__global__ __launch_bounds__(256) void k_pre(const float* __restrict__ x,
                                             float* __restrict__ pooled,
                                             ushort_t* __restrict__ xbu,
                                             const float* __restrict__ ipw,
                                             ushort_t* __restrict__ Wqb,
                                             const float* __restrict__ opw,
                                             ushort_t* __restrict__ Wob) {
    int bx = blockIdx.x;
    int t = threadIdx.x;
    if (bx < 2048) {
        const float4* row4 = (const float4*)(x + (size_t)bx * 4096);
        ushort_t* xw = xbu + (size_t)bx * 4096;
        float s = 0.f;
        for (int i = t; i < 1024; i += 256) {
            float4 v = row4[i];
            s += (v.x + v.y) + (v.z + v.w);
            uint2 u;
            u.x = pk_rne(v.x, v.y);
            u.y = pk_rne(v.z, v.w);
            *(uint2*)(xw + i * 4) = u;
        }
        __shared__ float red[256];
        red[t] = s;
        __syncthreads();
        for (int o = 128; o > 0; o >>= 1) {
            if (t < o) red[t] += red[t + o];
            __syncthreads();
        }
        if (t == 0) pooled[bx] = red[0] * (1.f / 4096.f);
    } else if (bx < 2144) {
        int i = (bx - 2048) * 256 + t;            // 0..24575
        float sc = (i < 8192) ? ALPHA : 1.f;      // Q-section rows
        const float4* s4 = (const float4*)ipw + (size_t)i * 2;
        float4 a = s4[0], b = s4[1];
        uint4 u;
        u.x = pk_rne(a.x * sc, a.y * sc); u.y = pk_rne(a.z * sc, a.w * sc);
        u.z = pk_rne(b.x * sc, b.y * sc); u.w = pk_rne(b.z * sc, b.w * sc);
        *(uint4*)(Wqb + (size_t)i * 8) = u;
    } else {
        int i = (bx - 2144) * 256 + t;            // 0..8191
        const float4* s4 = (const float4*)opw + (size_t)i * 2;
        float4 a = s4[0], b = s4[1];
        uint4 u;
        u.x = pk_rne(a.x, a.y); u.y = pk_rne(a.z, a.w);
        u.z = pk_rne(b.x, b.y); u.w = pk_rne(b.z, b.w);
        *(uint4*)(Wob + (size_t)i * 8) = u;
    }
}

// ------- Kernel 1b (fallback when ws too small for early Wob) ----------------
__global__ __launch_bounds__(256) void k_cvt(const float* __restrict__ src,
                                             ushort_t* __restrict__ dst, int n8,
                                             int scale_n8, float scale) {
    int i = blockIdx.x * 256 + threadIdx.x;
    if (i >= n8) return;
    float sc = (i < scale_n8) ? scale : 1.f;
    const float4* s = (const float4*)src + (size_t)i * 2;
    float4 a = s[0], b = s[1];
    uint4 u;
    u.x = pk_rne(a.x * sc, a.y * sc); u.y = pk_rne(a.z * sc, a.w * sc);
    u.z = pk_rne(b.x * sc, b.y * sc); u.w = pk_rne(b.z * sc, b.w * sc);
    *(uint4*)(dst + (size_t)i * 8) = u;
}

// ---------------- Kernel 1 (fallback only): SE MLP -> ca[b][c] ---------------
__global__ __launch_bounds__(256) void k_se(const float* __restrict__ pooled,
                                            const float* __restrict__ w1,
                                            const float* __restrict__ b1,
                                            const float* __restrict__ w2,
                                            const float* __restrict__ b2,
                                            float* __restrict__ ca) {
    __shared__ float sp[2048];
    __shared__ float sh1[512];
    int t = threadIdx.x;
    for (int i = t; i < 2048; i += 256) sp[i] = pooled[i];
    __syncthreads();
    for (int o = t; o < 512; o += 256) {
        int b = o >> 6, m = o & 63;
        float s = b1[m];
        const float* wr = w1 + (size_t)m * 256;
        const float* pr = sp + b * 256;
        for (int c = 0; c < 256; c++) s += pr[c] * wr[c];
        sh1[o] = s > 0.f ? s : 0.f;
    }
    __syncthreads();
    for (int o = t; o < 2048; o += 256) {
        int b = o >> 8, m = o & 255;
        float s = b2[m];
        const float* wr = w2 + (size_t)m * 64;
        const float* hr = sh1 + b * 64;
        for (int c = 0; c < 64; c++) s += hr[c] * wr[c];
        ca[o] = 1.f / (1.f + __expf(-s));
    }
}

// --- Kernel 1c: inline-SE + gate + window-permute, reads xbu (bf16) ----------
#define GPAD 524
__global__ __launch_bounds__(256) void k_gate(const ushort_t* __restrict__ xbu,
                                              const float* __restrict__ pooled,
                                              const float* __restrict__ w1,
                                              const float* __restrict__ b1,
                                              const float* __restrict__ w2,
                                              const float* __restrict__ b2,
                                              ushort_t* __restrict__ Ab) {
    __shared__ __align__(16) ushort_t Ls[32 * GPAD];
    __shared__ float sh1[64];
    __shared__ float sca[32];
    int bx = blockIdx.x;
    int b = bx >> 6, hw = (bx >> 3) & 7, c0 = (bx & 7) * 32;
    int t = threadIdx.x;
    // inline SE: h1 = relu(pooled[b] @ w1^T + b1)
    if (t < 64) {
        float s = b1[t];
        const float4* wr = (const float4*)(w1 + (size_t)t * 256);
        const float4* pr = (const float4*)(pooled + b * 256);
        for (int c = 0; c < 64; c++) {
            float4 wv = wr[c], pv = pr[c];
            s += pv.x * wv.x + pv.y * wv.y + pv.z * wv.z + pv.w * wv.w;
        }
        sh1[t] = s > 0.f ? s : 0.f;
    }
    __syncthreads();
    // ca[c0+t] = sigmoid(h1 @ w2[c0+t]^T + b2)
    if (t < 32) {
        int m = c0 + t;
        float s = b2[m];
        const float* wr = w2 + (size_t)m * 64;
        for (int j = 0; j < 64; j++) s += sh1[j] * wr[j];
        sca[t] = 1.f / (1.f + __expf(-s));
    }
    __syncthreads();
    const uint2* xb = (const uint2*)(xbu + ((size_t)(b * 256 + c0) * 64 + hw * 8) * 64);
#pragma unroll
    for (int i = 0; i < 16; i++) {
        int f = i * 256 + t;
        int ch = f >> 7, rem = f & 127, r = rem >> 4, w4 = rem & 15;
        uint2 v = xb[(size_t)ch * 1024 + r * 16 + w4];   // 4 bf16
        float g = sca[ch];
        float x0 = bfh(v.x & 0xffffu), x1 = bfh(v.x >> 16);
        float x2 = bfh(v.y & 0xffffu), x3 = bfh(v.y >> 16);
        uint2 u;
        u.x = pk_rne(x0 * g, x1 * g);
        u.y = pk_rne(x2 * g, x3 * g);
        *(uint2*)&Ls[ch * GPAD + r * 64 + w4 * 4] = u;
    }
    __syncthreads();
#pragma unroll
    for (int i = 0; i < 8; i++) {
        int q = i * 256 + t;
        int rr = q >> 2, part = q & 3;
        int ww = rr >> 6, p = rr & 63;
        int px = (p >> 3) * 64 + ww * 8 + (p & 7);
        const ushort_t* ls = &Ls[part * 8 * GPAD + px];
        uint4 u;
        u.x = (uint_t)ls[0]        | ((uint_t)ls[GPAD] << 16);
        u.y = (uint_t)ls[2 * GPAD] | ((uint_t)ls[3 * GPAD] << 16);
        u.z = (uint_t)ls[4 * GPAD] | ((uint_t)ls[5 * GPAD] << 16);
        u.w = (uint_t)ls[6 * GPAD] | ((uint_t)ls[7 * GPAD] << 16);
        size_t m = (size_t)(((hw * 8 + ww) * 8 + b) * 64 + p);
        *(uint4*)(Ab + m * 256 + c0 + part * 8) = u;
    }
}

// ------- Kernel 2: QKV GEMM, 64m x 128n, dual 64-k buffers, one drain/128k ---
// r11: stage BOTH 64-k halves (As[2]/Bs[2], 48 KiB) then ONE vmcnt(0)+barrier
// covers 32 MFMA/wave. 3 blocks/CU (lb(256,3)), grid 3072. XCD map: per XCD
// the 6 (sec,nh) blocks of an m-panel are consecutive -> A panel L2-served 6x.
__global__ __launch_bounds__(256, 3) void k_gemm_qkv4(const ushort_t* __restrict__ A,
                                                      const ushort_t* __restrict__ Bw,
                                                      const float* __restrict__ bias,
                                                      ushort_t* __restrict__ Qb,
                                                      ushort_t* __restrict__ Kb,
                                                      ushort_t* __restrict__ Vb) {
    __shared__ __align__(16) ushort_t As[2][4096];   // 2 x 8 KiB
    __shared__ __align__(16) ushort_t Bs[2][8192];   // 2 x 16 KiB
    int tid = threadIdx.x;
    int lane = tid & 63, wave = tid >> 6;
    int wm = wave >> 1, wn = wave & 1;             // wave tile: 32m x 64n
    int col = lane & 15, quad = lane >> 4;
    int orig = blockIdx.x;                // 0..3071
    int xcd = orig & 7;
    int i384 = orig >> 3;                 // 0..383
    int mi = i384 / 6;                    // 0..63 local m-panel
    int r6 = i384 - mi * 6;               // 0..5
    int sec = r6 >> 1, nh = r6 & 1;
    int m0 = (xcd * 64 + mi) * 64;
    const ushort_t* Bsec = Bw + ((size_t)sec << 16) + ((size_t)nh * 128) * 256;

    int cbase = wave * 64 + lane;
    const ushort_t* asrc[2];
    const ushort_t* bsrc[4];
#pragma unroll
    for (int q = 0; q < 2; q++) {
        int c = q * 256 + cbase;          // A chunk 0..511
        int row = c >> 3;                 // 0..63
        int kp = (c & 7) ^ (row & 7);     // pre-swizzled source k-part
        asrc[q] = A + (size_t)(m0 + row) * 256 + kp * 8;
    }
#pragma unroll
    for (int q = 0; q < 4; q++) {
        int c = q * 256 + cbase;          // B chunk 0..1023
        int row = c >> 3;                 // 0..127
        int kp = (c & 7) ^ (row & 7);
        bsrc[q] = Bsec + (size_t)row * 256 + kp * 8;
    }

    f32x4 acc[2][4];
#pragma unroll
    for (int i = 0; i < 2; i++)
#pragma unroll
        for (int j = 0; j < 4; j++) acc[i][j] = (f32x4){0.f, 0.f, 0.f, 0.f};

    for (int t2 = 0; t2 < 2; t2++) {
        int k0 = t2 * 128;
#pragma unroll
        for (int h = 0; h < 2; h++) {     // two 64-k halves, back-to-back issue
#pragma unroll
            for (int q = 0; q < 2; q++)
                gl_lds16(asrc[q] + k0 + h * 64, &As[h][(q * 4 + wave) * 512]);
#pragma unroll
            for (int q = 0; q < 4; q++)
                gl_lds16(bsrc[q] + k0 + h * 64, &Bs[h][(q * 4 + wave) * 512]);
        }
        __syncthreads();                  // single drain covers 128 k
#pragma unroll
        for (int h = 0; h < 2; h++) {
            const ushort_t* Ac = As[h];
            const ushort_t* Bc = Bs[h];
#pragma unroll
            for (int kk = 0; kk < 2; kk++) {
                bf16x8 af[2], bfg[4];
#pragma unroll
                for (int i = 0; i < 2; i++) {
                    int row = wm * 32 + i * 16 + col;
                    af[i] = *(const bf16x8*)&Ac[row * 64 + ((kk * 4 + quad) ^ (row & 7)) * 8];
                }
#pragma unroll
                for (int j = 0; j < 4; j++) {
                    int row = wn * 64 + j * 16 + col;
                    bfg[j] = *(const bf16x8*)&Bc[row * 64 + ((kk * 4 + quad) ^ (row & 7)) * 8];
                }
#pragma unroll
                for (int i = 0; i < 2; i++)
#pragma unroll
                    for (int j = 0; j < 4; j++)
                        acc[i][j] = __builtin_amdgcn_mfma_f32_16x16x32_bf16(bfg[j], af[i], acc[i][j], 0, 0, 0);
            }
        }
        __syncthreads();
    }

    // epilogue: n_sec = nh*128 + wn*64 + j*16 + quad*4 + r; m = m0+wm*32+i*16+col
    ushort_t* dst = (sec == 0) ? Qb : (sec == 1) ? Kb : Vb;
    float bsc = (sec == 0) ? ALPHA : 1.f;    // Q bias folded with softmax scale
    int nb0 = nh * 128 + wn * 64 + quad * 4;
#pragma unroll
    for (int j = 0; j < 4; j++) {
        float4 bv = *(const float4*)(bias + sec * 256 + nb0 + j * 16);
        bv.x *= bsc; bv.y *= bsc; bv.z *= bsc; bv.w *= bsc;
#pragma unroll
        for (int i = 0; i < 2; i++) {
            int m = m0 + wm * 32 + i * 16 + col;
            uint2 st;
            st.x = pk_rne(acc[i][j][0] + bv.x, acc[i][j][1] + bv.y);
            st.y = pk_rne(acc[i][j][2] + bv.z, acc[i][j][3] + bv.w);
            *(uint2*)(dst + (size_t)m * 256 + nb0 + j * 16) = st;
        }
    }
}

// ---------------- Kernel 3: MFMA attention per (pixel p, head h) ----------------
// 512 threads (8 waves, 4 q-tiles each), single-shot staging of all 512 keys.
// Ks[key][32] with chunk XOR (quad ^ (key>>3)&3): conflict-free b128 reads.
// Vt[vc][512] transposed; swizzle swz(vc) = (vc&7) ^ ((vc>>3)<<1) on write AND read.
// Q pre-scaled by ALPHA (log2 domain) -> softmax numerator is bare v_exp_f32.
// qsum via ones-operand MFMA (accS) — row-sum on the matrix pipe (r10).
__global__ __launch_bounds__(512, 4) void k_attn(const ushort_t* __restrict__ Qb,
                                                 const ushort_t* __restrict__ Kb,
                                                 const ushort_t* __restrict__ Vb,
                                                 ushort_t* __restrict__ AO) {
    __shared__ __align__(16) ushort_t Ks[512 * 32];   // 32 KiB
    __shared__ __align__(16) ushort_t Vt[32 * 512];   // 32 KiB
    int p = blockIdx.x >> 3, h = blockIdx.x & 7;
    int tid = threadIdx.x;
    int lane = tid & 63, wave = tid >> 6;             // wave 0..7
    int col = lane & 15, quad = lane >> 4;

    // K staging: unit = (key, oct); bf16x8 -> swizzled chunk
#pragma unroll
    for (int it = 0; it < 4; it++) {
        int u = it * 512 + tid;
        int key = u >> 2, oct = u & 3;
        size_t grow = ((size_t)(key * 64 + p)) * 256 + h * 32 + oct * 8;
        int ck = oct ^ ((key >> 3) & 3);
        *(bf16x8*)&Ks[key * 32 + ck * 8] = *(const bf16x8*)(Kb + grow);
    }
    // V staging: unit = (key-pair, oct); pack 2 keys/chan -> ds_write_b32
#pragma unroll
    for (int it = 0; it < 2; it++) {
        int u = it * 512 + tid;
        int kp = u >> 2, oct = u & 3;
        int k0 = kp * 2;
        size_t g0 = ((size_t)(k0 * 64 + p)) * 256 + h * 32 + oct * 8;
        bf16x8 v0 = *(const bf16x8*)(Vb + g0);
        bf16x8 v1 = *(const bf16x8*)(Vb + g0 + 16384);   // key+1 row
        int kc = kp >> 2;                                // key>>3
#pragma unroll
        for (int j = 0; j < 8; j++) {
            int vc = oct * 8 + j;
            int kcs = kc ^ (vc & 7) ^ ((vc >> 3) << 1);
            uint_t pkv = (uint_t)(ushort_t)v0[j] | ((uint_t)(ushort_t)v1[j] << 16);
            *(uint_t*)&Vt[vc * 512 + kcs * 8 + (k0 & 7)] = pkv;
        }
    }

    // Q fragments (independent global loads, overlap with staging)
    bf16x8 qfrag[4];
#pragma unroll
    for (int i = 0; i < 4; i++) {
        int qt = wave * 4 + i;
        qfrag[i] = *(const bf16x8*)(Qb + ((size_t)((qt * 16 + col) * 64 + p)) * 256 + h * 32 + quad * 8);
    }

    f32x4 O0[4], O1[4], accS[4];
#pragma unroll
    for (int i = 0; i < 4; i++) {
        O0[i] = (f32x4){0.f, 0.f, 0.f, 0.f};
        O1[i] = (f32x4){0.f, 0.f, 0.f, 0.f};
        accS[i] = (f32x4){0.f, 0.f, 0.f, 0.f};
    }
    const f32x4 zero = {0.f, 0.f, 0.f, 0.f};
    const short OB = (short)0x3F80;                  // bf16 1.0
    const bf16x8 ones8 = {OB, OB, OB, OB, OB, OB, OB, OB};
    int R = col >> 2, r4 = lane & 3;
    int krow0 = 8 * R + r4;                  // kf0 row offset; kf1 = +4
    int vc0 = col, vc1 = col + 16;
    int sw0 = (vc0 & 7) ^ ((vc0 >> 3) << 1); // full swizzle, matches write
    int sw1 = (vc1 & 7) ^ ((vc1 >> 3) << 1);

    __syncthreads();

    for (int c = 0; c < 512; c += 32) {
        int row0 = c + krow0;
        int row1 = row0 + 4;
        int ckq = quad ^ ((row0 >> 3) & 3);  // same for row1 (r4<4)
        bf16x8 kf0 = *(const bf16x8*)&Ks[row0 * 32 + ckq * 8];
        bf16x8 kf1 = *(const bf16x8*)&Ks[row1 * 32 + ckq * 8];
        int kc = (c >> 3) + quad;
        bf16x8 vf0 = *(const bf16x8*)&Vt[vc0 * 512 + ((kc ^ sw0) * 8)];
        bf16x8 vf1 = *(const bf16x8*)&Vt[vc1 * 512 + ((kc ^ sw1) * 8)];
#pragma unroll
        for (int i = 0; i < 4; i++) {
            __builtin_amdgcn_s_setprio(1);
            f32x4 s0 = __builtin_amdgcn_mfma_f32_16x16x32_bf16(kf0, qfrag[i], zero, 0, 0, 0);
            f32x4 s1 = __builtin_amdgcn_mfma_f32_16x16x32_bf16(kf1, qfrag[i], zero, 0, 0, 0);
            __builtin_amdgcn_s_setprio(0);
            float p0[4], p1[4];
#pragma unroll
            for (int r = 0; r < 4; r++) {
                p0[r] = __builtin_amdgcn_exp2f(s0[r]);
                p1[r] = __builtin_amdgcn_exp2f(s1[r]);
            }
            union { uint_t u[4]; bf16x8 v; } pb;
            pb.u[0] = pk2(p0[0], p0[1]);
            pb.u[1] = pk2(p0[2], p0[3]);
            pb.u[2] = pk2(p1[0], p1[1]);
            pb.u[3] = pk2(p1[2], p1[3]);
            __builtin_amdgcn_s_setprio(1);
            O0[i] = __builtin_amdgcn_mfma_f32_16x16x32_bf16(vf0, pb.v, O0[i], 0, 0, 0);
            O1[i] = __builtin_amdgcn_mfma_f32_16x16x32_bf16(vf1, pb.v, O1[i], 0, 0, 0);
            accS[i] = __builtin_amdgcn_mfma_f32_16x16x32_bf16(ones8, pb.v, accS[i], 0, 0, 0);
            __builtin_amdgcn_s_setprio(0);
        }
    }

#pragma unroll
    for (int i = 0; i < 4; i++) {
        float inv = 1.f / accS[i][0];        // full 512-key sum, uniform in quad
        int qt = wave * 4 + i;
        ushort_t* dst = AO + ((size_t)((qt * 16 + col) * 64 + p)) * 256 + h * 32;
        uint2 st0, st1;
        st0.x = pk_rne(O0[i][0] * inv, O0[i][1] * inv);
        st0.y = pk_rne(O0[i][2] * inv, O0[i][3] * inv);
        st1.x = pk_rne(O1[i][0] * inv, O1[i][1] * inv);
        st1.y = pk_rne(O1[i][2] * inv, O1[i][3] * inv);
        *(uint2*)(dst + quad * 4) = st0;
        *(uint2*)(dst + 16 + quad * 4) = st1;
    }
}

// --- Kernel 4: out-proj GEMM + residual + scatter, m97-structure -------------
__global__ __launch_bounds__(256, 4) void k_gemm_out3(const ushort_t* __restrict__ A,
                                                      const ushort_t* __restrict__ Bw,
                                                      const float* __restrict__ bias,
                                                      const ushort_t* __restrict__ G,
                                                      const float* __restrict__ x,
                                                      const float* __restrict__ ca,
                                                      float* __restrict__ out) {
    __shared__ __align__(16) ushort_t As[4096];    // 8 KiB: 64 rows x 64 k
    __shared__ __align__(16) ushort_t Bs[8192];    // 16 KiB: 128 rows x 64 k
    int tid = threadIdx.x;
    int lane = tid & 63, wave = tid >> 6;
    int wm = wave >> 1, wn = wave & 1;             // wave tile: 32m x 64n
    int col = lane & 15, quad = lane >> 4;
    int orig = blockIdx.x;                // 0..1023
    int xcd = orig & 7;
    int i128 = orig >> 3;                 // 0..127
    int mi = i128 >> 1;                   // 0..63 local m-panel (token)
    int ns = i128 & 1;
    int m0 = (xcd * 64 + mi) * 64;        // token base row
    int n0 = ns * 128;

    int cbase = wave * 64 + lane;
    const ushort_t* asrc[2];
    const ushort_t* bsrc[4];
#pragma unroll
    for (int q = 0; q < 2; q++) {
        int c = q * 256 + cbase;          // A chunk 0..511
        int row = c >> 3;                 // 0..63
        int kp = (c & 7) ^ (row & 7);
        asrc[q] = A + (size_t)(m0 + row) * 256 + kp * 8;
    }
#pragma unroll
    for (int q = 0; q < 4; q++) {
        int c = q * 256 + cbase;          // B chunk 0..1023
        int row = c >> 3;                 // 0..127
        int kp = (c & 7) ^ (row & 7);
        bsrc[q] = Bw + (size_t)(n0 + row) * 256 + kp * 8;
    }

    f32x4 acc[2][4];
#pragma unroll
    for (int i = 0; i < 2; i++)
#pragma unroll
        for (int j = 0; j < 4; j++) acc[i][j] = (f32x4){0.f, 0.f, 0.f, 0.f};

    for (int t = 0; t < 4; t++) {
        int k0 = t * 64;
#pragma unroll
        for (int q = 0; q < 2; q++) gl_lds16(asrc[q] + k0, &As[(q * 4 + wave) * 512]);
#pragma unroll
        for (int q = 0; q < 4; q++) gl_lds16(bsrc[q] + k0, &Bs[(q * 4 + wave) * 512]);
        __syncthreads();
#pragma unroll
        for (int kk = 0; kk < 2; kk++) {
            bf16x8 af[2], bfg[4];
#pragma unroll
            for (int i = 0; i < 2; i++) {
                int row = wm * 32 + i * 16 + col;
                af[i] = *(const bf16x8*)&As[row * 64 + ((kk * 4 + quad) ^ (row & 7)) * 8];
            }
#pragma unroll
            for (int j = 0; j < 4; j++) {
                int row = wn * 64 + j * 16 + col;
                bfg[j] = *(const bf16x8*)&Bs[row * 64 + ((kk * 4 + quad) ^ (row & 7)) * 8];
            }
#pragma unroll
            for (int i = 0; i < 2; i++)
#pragma unroll
                for (int j = 0; j < 4; j++)
                    acc[i][j] = __builtin_amdgcn_mfma_f32_16x16x32_bf16(bfg[j], af[i], acc[i][j], 0, 0, 0);
        }
        __syncthreads();
    }

    // epilogue: block = one token lw = m0>>6; px = wm*32 + i*16 + col
    int lw = m0 >> 6;
    int b = lw & 7, w_idx = lw >> 3;
    int hw = w_idx >> 3, ww = w_idx & 7;
    if (G != nullptr) {
#pragma unroll
        for (int j = 0; j < 4; j++) {
            int nbase = n0 + wn * 64 + j * 16 + quad * 4;
            float4 bv = *(const float4*)(bias + nbase);
#pragma unroll
            for (int i = 0; i < 2; i++) {
                int px = wm * 32 + i * 16 + col;
                // residual = x*ca at NORMAL spatial (h=w_idx, w=px)
                int mres = ((hw * 8 + (px >> 3)) * 8 + b) * 64 + ww * 8 + (px & 7);
                uint2 gv = *(const uint2*)(G + (size_t)mres * 256 + nbase);
                float g0 = bfh(gv.x & 0xffffu), g1 = bfh(gv.x >> 16);
                float g2 = bfh(gv.y & 0xffffu), g3 = bfh(gv.y >> 16);
                size_t ob = (((size_t)b * 256 + nbase) * 64 + w_idx) * 64 + px;
                out[ob]            = acc[i][j][0] + bv.x + g0;
                out[ob + 4096]     = acc[i][j][1] + bv.y + g1;
                out[ob + 2 * 4096] = acc[i][j][2] + bv.z + g2;
                out[ob + 3 * 4096] = acc[i][j][3] + bv.w + g3;
            }
        }
    } else {
#pragma unroll
        for (int j = 0; j < 4; j++) {
            int nbase = n0 + wn * 64 + j * 16 + quad * 4;
            float4 bv = *(const float4*)(bias + nbase);
            float4 cv = *(const float4*)(ca + b * 256 + nbase);
#pragma unroll
            for (int i = 0; i < 2; i++) {
                int px = wm * 32 + i * 16 + col;
#pragma unroll
                for (int r = 0; r < 4; r++) {
                    int n = nbase + r;
                    float bias_r = (r == 0) ? bv.x : (r == 1) ? bv.y : (r == 2) ? bv.z : bv.w;
                    float ca_r = (r == 0) ? cv.x : (r == 1) ? cv.y : (r == 2) ? cv.z : cv.w;
                    size_t oi = (((size_t)b * 256 + n) * 64 + w_idx) * 64 + px;
                    out[oi] = acc[i][j][r] + bias_r + x[oi] * ca_r;
                }
            }
        }
    }
}

extern "C" void kernel_launch(void* const* d_in, const int* in_sizes, int n_in,
                              void* d_out, int out_size, void* d_ws, size_t ws_size,
                              hipStream_t stream) {
    const float* x     = (const float*)d_in[0];
    const float* ca_w1 = (const float*)d_in[1];
    const float* ca_b1 = (const float*)d_in[2];
    const float* ca_w2 = (const float*)d_in[3];
    const float* ca_b2 = (const float*)d_in[4];
    const float* ipw   = (const float*)d_in[5];
    const float* ipb   = (const float*)d_in[6];
    const float* opw   = (const float*)d_in[7];
    const float* opb   = (const float*)d_in[8];
    float* out = (float*)d_out;

    char* ws = (char*)d_ws;
    const size_t MB16 = 16777216ull;
    ushort_t* Qb = (ushort_t*)(ws + 0);          // 16 MiB; AO aliases this
    ushort_t* Kb = (ushort_t*)(ws + MB16);       // 16 MiB; xbu aliases this pre-qkv
    ushort_t* Vb = (ushort_t*)(ws + 2 * MB16);   // 16 MiB
    float* pooled = (float*)(ws + 3 * MB16);     // 8 KiB
    float* ca     = (float*)(ws + 3 * MB16 + 8192);

    // xbu = bf16(x), written by k_pre, consumed by k_gate, dead before qkv4
    // overwrites Kb (stream-ordered) — zero extra memory in both paths.
    ushort_t* xbu = Kb;

    // big_ws layout: Wob @ +16 KiB, Wqb @ +160 KiB, Ab @ 49 MiB (16 MiB).
    const size_t WOB_OFF = 3 * MB16 + 16384;
    const size_t WQB_OFF = 3 * MB16 + 163840;
    const size_t AB_OFF  = 3 * MB16 + 1048576;
    bool big_ws = (ws_size >= AB_OFF + MB16);

    ushort_t* Wob, *Wqb, *Ab;
    const ushort_t* G;
    if (big_ws) {
        Wob = (ushort_t*)(ws + WOB_OFF);
        Wqb = (ushort_t*)(ws + WQB_OFF);
        Ab  = (ushort_t*)(ws + AB_OFF);
        G   = Ab;                                 // residual from gated bf16
    } else {
        // fallback: d_out as scratch (as round 6); residual from x*ca
        Ab  = (ushort_t*)d_out;
        Wqb = (ushort_t*)((char*)d_out + MB16);
        Wob = Vb;                                 // late cvt into Vb post-attn
        G   = nullptr;
    }

    k_pre<<<big_ws ? 2176 : 2144, 256, 0, stream>>>(x, pooled, xbu, ipw, Wqb, opw, Wob);
    if (!big_ws) k_se<<<1, 256, 0, stream>>>(pooled, ca_w1, ca_b1, ca_w2, ca_b2, ca);
    k_gate<<<512, 256, 0, stream>>>(xbu, pooled, ca_w1, ca_b1, ca_w2, ca_b2, Ab);
    k_gemm_qkv4<<<3072, 256, 0, stream>>>(Ab, Wqb, ipb, Qb, Kb, Vb);
    k_attn<<<512, 512, 0, stream>>>(Qb, Kb, Vb, Qb /* AO aliases Q */);
    if (!big_ws) k_cvt<<<32, 256, 0, stream>>>(opw, Vb, 8192, 0, 1.f);
    k_gemm_out3<<<1024, 256, 0, stream>>>(Qb, Wob, opb, G, x, ca, out);
}

// Round 14
// 179.334 us; speedup vs baseline: 1.0534x; 1.0443x over previous
//
#include <hip/hip_runtime.h>
#include <hip/hip_bf16.h>
#include <math.h>

// Problem constants (B=8, C=256, H=W=64, WS=8, NH=8)
// DTYPES: all inputs fp32, output fp32 (harness compares in bf16 space).
// === This is the round-11 kernel (best verified: 183.2 us), restored. ===
// Regression ledger (do NOT retry):
//  r12: single-x-pass via per-batch gated weight copies -> +5.7us (coalescing
//       loss + 8x B-footprint + redundant-SE serial cost).
//  r13: xbu=bf16(x) side-write in k_pre, k_gate reads bf16 -> +4.1us (k_pre is
//       read-bound; +16MB writes there cost more than k_gate's -48MB reads
//       saved — the two kernels' costs don't trade linearly).
// ws layout (fill evidence: ws = 256 MiB; big_ws path used when >= 65 MiB):
//   Q @ 0, K @ 16 MiB, V @ 32 MiB  [32768][256] bf16 each (AO aliases Q)
//   pooled @ 48 MiB (8 KiB), ca @ +8 KiB, Wob @ +16 KiB (128 KiB),
//   Wqb @ +160 KiB (384 KiB), Ab @ 49 MiB (16 MiB).
// big_ws: d_out holds ONLY the final output; k_gemm_out3 residual from
// Ab = bf16(x*ca) at the re-permuted row (output quirk: H=window idx, W=pixel):
//   mres = ((hw*8+(px>>3))*8+b)*64 + ww*8+(px&7), hw=w_idx>>3, ww=w_idx&7.
// SE fusion: k_gate computes its own 32-channel ca slice inline (r8).
// Softmax scale fold: Q-section of in_proj W pre-scaled by ALPHA = log2(e)/sqrt(32).
// Attn: ones-MFMA softmax denominator (r10, -3.4us verified).
// GEMM ledger: source dbuf defeated by vmcnt(0) (r4); acc[4][8] VGPR blowup
// -> 2 blocks/CU (r5-r8); out3-geometry 64mx128n acc[2][4] lb(256,4) proven
// (r9, -10.6us); qkv dual 64-k buffer, one drain/128k, 3 blocks/CU (r11).

typedef unsigned short ushort_t;
typedef unsigned int uint_t;
typedef __attribute__((ext_vector_type(8))) short bf16x8;
typedef __attribute__((ext_vector_type(4))) float f32x4;

#define ALPHA 0.25503486f   // log2(e) / sqrt(32)

__device__ __forceinline__ uint_t pk_rne(float a, float b) {     // bf16 pack, RNE
    __hip_bfloat16 ha = __float2bfloat16(a), hb = __float2bfloat16(b);
    ushort_t ua = *(ushort_t*)&ha, ub = *(ushort_t*)&hb;
    return (uint_t)ua | ((uint_t)ub << 16);
}

// bf16 pack (truncate) via single v_perm_b32: low16 = hi(a), high16 = hi(b)
__device__ __forceinline__ uint_t pk2(float a, float b) {
    union { float f; uint_t u; } ua, ub; ua.f = a; ub.f = b;
    return __builtin_amdgcn_perm(ua.u, ub.u, 0x03020706u);
}

__device__ __forceinline__ float bfh(uint_t h) {                 // bf16 bits -> f32
    union { uint_t u; float f; } t; t.u = h << 16; return t.f;
}

// async global->LDS 16B: LDS dest must be wave-uniform base (+lane*16 implicit)
__device__ __forceinline__ void gl_lds16(const ushort_t* g, ushort_t* l) {
    __builtin_amdgcn_global_load_lds(
        (__attribute__((address_space(1))) unsigned int*)(g),
        (__attribute__((address_space(3))) unsigned int*)(l), 16, 0, 0);
}

// ------ Kernel 0: fused pre-pass. blocks 0..2047: avg-pool row bc=bx.
//        blocks 2048..2143: in_proj W fp32->bf16 (Q rows scaled by ALPHA).
//        blocks 2144..2175 (big_ws): out_proj W fp32->bf16. -------------------
__global__ __launch_bounds__(256) void k_pre(const float* __restrict__ x,
                                             float* __restrict__ pooled,
                                             const float* __restrict__ ipw,
                                             ushort_t* __restrict__ Wqb,
                                             const float* __restrict__ opw,
                                             ushort_t* __restrict__ Wob) {
    int bx = blockIdx.x;
    int t = threadIdx.x;
    if (bx < 2048) {
        const float4* row4 = (const float4*)(x + (size_t)bx * 4096);
        float s = 0.f;
        for (int i = t; i < 1024; i += 256) {
            float4 v = row4[i];
            s += v.x + v.y + v.z + v.w;
        }
        __shared__ float red[256];
        red[t] = s;
        __syncthreads();
        for (int o = 128; o > 0; o >>= 1) {
            if (t < o) red[t] += red[t + o];
            __syncthreads();
        }
        if (t == 0) pooled[bx] = red[0] * (1.f / 4096.f);
    } else if (bx < 2144) {
        int i = (bx - 2048) * 256 + t;            // 0..24575
        float sc = (i < 8192) ? ALPHA : 1.f;      // Q-section rows
        const float4* s4 = (const float4*)ipw + (size_t)i * 2;
        float4 a = s4[0], b = s4[1];
        uint4 u;
        u.x = pk_rne(a.x * sc, a.y * sc); u.y = pk_rne(a.z * sc, a.w * sc);
        u.z = pk_rne(b.x * sc, b.y * sc); u.w = pk_rne(b.z * sc, b.w * sc);
        *(uint4*)(Wqb + (size_t)i * 8) = u;
    } else {
        int i = (bx - 2144) * 256 + t;            // 0..8191
        const float4* s4 = (const float4*)opw + (size_t)i * 2;
        float4 a = s4[0], b = s4[1];
        uint4 u;
        u.x = pk_rne(a.x, a.y); u.y = pk_rne(a.z, a.w);
        u.z = pk_rne(b.x, b.y); u.w = pk_rne(b.z, b.w);
        *(uint4*)(Wob + (size_t)i * 8) = u;
    }
}

// ------- Kernel 1b (fallback when ws too small for early Wob) ----------------
__global__ __launch_bounds__(256) void k_cvt(const float* __restrict__ src,
                                             ushort_t* __restrict__ dst, int n8,
                                             int scale_n8, float scale) {
    int i = blockIdx.x * 256 + threadIdx.x;
    if (i >= n8) return;
    float sc = (i < scale_n8) ? scale : 1.f;
    const float4* s = (const float4*)src + (size_t)i * 2;
    float4 a = s[0], b = s[1];
    uint4 u;
    u.x = pk_rne(a.x * sc, a.y * sc); u.y = pk_rne(a.z * sc, a.w * sc);
    u.z = pk_rne(b.x * sc, b.y * sc); u.w = pk_rne(b.z * sc, b.w * sc);
    *(uint4*)(dst + (size_t)i * 8) = u;
}

// ---------------- Kernel 1 (fallback only): SE MLP -> ca[b][c] ---------------
__global__ __launch_bounds__(256) void k_se(const float* __restrict__ pooled,
                                            const float* __restrict__ w1,
                                            const float* __restrict__ b1,
                                            const float* __restrict__ w2,
                                            const float* __restrict__ b2,
                                            float* __restrict__ ca) {
    __shared__ float sp[2048];
    __shared__ float sh1[512];
    int t = threadIdx.x;
    for (int i = t; i < 2048; i += 256) sp[i] = pooled[i];
    __syncthreads();
    for (int o = t; o < 512; o += 256) {
        int b = o >> 6, m = o & 63;
        float s = b1[m];
        const float* wr = w1 + (size_t)m * 256;
        const float* pr = sp + b * 256;
        for (int c = 0; c < 256; c++) s += pr[c] * wr[c];
        sh1[o] = s > 0.f ? s : 0.f;
    }
    __syncthreads();
    for (int o = t; o < 2048; o += 256) {
        int b = o >> 8, m = o & 255;
        float s = b2[m];
        const float* wr = w2 + (size_t)m * 64;
        const float* hr = sh1 + b * 64;
        for (int c = 0; c < 64; c++) s += hr[c] * wr[c];
        ca[o] = 1.f / (1.f + __expf(-s));
    }
}

// --- Kernel 1c: inline-SE + gate + window-permute + bf16 -> Ab[32768][256] ---
#define GPAD 524
__global__ __launch_bounds__(256) void k_gate(const float* __restrict__ x,
                                              const float* __restrict__ pooled,
                                              const float* __restrict__ w1,
                                              const float* __restrict__ b1,
                                              const float* __restrict__ w2,
                                              const float* __restrict__ b2,
                                              ushort_t* __restrict__ Ab) {
    __shared__ __align__(16) ushort_t Ls[32 * GPAD];
    __shared__ float sh1[64];
    __shared__ float sca[32];
    int bx = blockIdx.x;
    int b = bx >> 6, hw = (bx >> 3) & 7, c0 = (bx & 7) * 32;
    int t = threadIdx.x;
    // inline SE: h1 = relu(pooled[b] @ w1^T + b1)
    if (t < 64) {
        float s = b1[t];
        const float4* wr = (const float4*)(w1 + (size_t)t * 256);
        const float4* pr = (const float4*)(pooled + b * 256);
        for (int c = 0; c < 64; c++) {
            float4 wv = wr[c], pv = pr[c];
            s += pv.x * wv.x + pv.y * wv.y + pv.z * wv.z + pv.w * wv.w;
        }
        sh1[t] = s > 0.f ? s : 0.f;
    }
    __syncthreads();
    // ca[c0+t] = sigmoid(h1 @ w2[c0+t]^T + b2)
    if (t < 32) {
        int m = c0 + t;
        float s = b2[m];
        const float* wr = w2 + (size_t)m * 64;
        for (int j = 0; j < 64; j++) s += sh1[j] * wr[j];
        sca[t] = 1.f / (1.f + __expf(-s));
    }
    __syncthreads();
    const float4* xb = (const float4*)(x + ((size_t)(b * 256 + c0) * 64 + hw * 8) * 64);
#pragma unroll
    for (int i = 0; i < 16; i++) {
        int f = i * 256 + t;
        int ch = f >> 7, rem = f & 127, r = rem >> 4, w4 = rem & 15;
        float4 v = xb[(size_t)ch * 1024 + r * 16 + w4];
        float g = sca[ch];
        uint2 u;
        u.x = pk_rne(v.x * g, v.y * g);
        u.y = pk_rne(v.z * g, v.w * g);
        *(uint2*)&Ls[ch * GPAD + r * 64 + w4 * 4] = u;
    }
    __syncthreads();
#pragma unroll
    for (int i = 0; i < 8; i++) {
        int q = i * 256 + t;
        int rr = q >> 2, part = q & 3;
        int ww = rr >> 6, p = rr & 63;
        int px = (p >> 3) * 64 + ww * 8 + (p & 7);
        const ushort_t* ls = &Ls[part * 8 * GPAD + px];
        uint4 u;
        u.x = (uint_t)ls[0]        | ((uint_t)ls[GPAD] << 16);
        u.y = (uint_t)ls[2 * GPAD] | ((uint_t)ls[3 * GPAD] << 16);
        u.z = (uint_t)ls[4 * GPAD] | ((uint_t)ls[5 * GPAD] << 16);
        u.w = (uint_t)ls[6 * GPAD] | ((uint_t)ls[7 * GPAD] << 16);
        size_t m = (size_t)(((hw * 8 + ww) * 8 + b) * 64 + p);
        *(uint4*)(Ab + m * 256 + c0 + part * 8) = u;
    }
}

// ------- Kernel 2: QKV GEMM, 64m x 128n, dual 64-k buffers, one drain/128k ---
// r11: stage BOTH 64-k halves (As[2]/Bs[2], 48 KiB) then ONE vmcnt(0)+barrier
// covers 32 MFMA/wave. 3 blocks/CU (lb(256,3)), grid 3072. XCD map: per XCD
// the 6 (sec,nh) blocks of an m-panel are consecutive -> A panel L2-served 6x.
__global__ __launch_bounds__(256, 3) void k_gemm_qkv4(const ushort_t* __restrict__ A,
                                                      const ushort_t* __restrict__ Bw,
                                                      const float* __restrict__ bias,
                                                      ushort_t* __restrict__ Qb,
                                                      ushort_t* __restrict__ Kb,
                                                      ushort_t* __restrict__ Vb) {
    __shared__ __align__(16) ushort_t As[2][4096];   // 2 x 8 KiB
    __shared__ __align__(16) ushort_t Bs[2][8192];   // 2 x 16 KiB
    int tid = threadIdx.x;
    int lane = tid & 63, wave = tid >> 6;
    int wm = wave >> 1, wn = wave & 1;             // wave tile: 32m x 64n
    int col = lane & 15, quad = lane >> 4;
    int orig = blockIdx.x;                // 0..3071
    int xcd = orig & 7;
    int i384 = orig >> 3;                 // 0..383
    int mi = i384 / 6;                    // 0..63 local m-panel
    int r6 = i384 - mi * 6;               // 0..5
    int sec = r6 >> 1, nh = r6 & 1;
    int m0 = (xcd * 64 + mi) * 64;
    const ushort_t* Bsec = Bw + ((size_t)sec << 16) + ((size_t)nh * 128) * 256;

    int cbase = wave * 64 + lane;
    const ushort_t* asrc[2];
    const ushort_t* bsrc[4];
#pragma unroll
    for (int q = 0; q < 2; q++) {
        int c = q * 256 + cbase;          // A chunk 0..511
        int row = c >> 3;                 // 0..63
        int kp = (c & 7) ^ (row & 7);     // pre-swizzled source k-part
        asrc[q] = A + (size_t)(m0 + row) * 256 + kp * 8;
    }
#pragma unroll
    for (int q = 0; q < 4; q++) {
        int c = q * 256 + cbase;          // B chunk 0..1023
        int row = c >> 3;                 // 0..127
        int kp = (c & 7) ^ (row & 7);
        bsrc[q] = Bsec + (size_t)row * 256 + kp * 8;
    }

    f32x4 acc[2][4];
#pragma unroll
    for (int i = 0; i < 2; i++)
#pragma unroll
        for (int j = 0; j < 4; j++) acc[i][j] = (f32x4){0.f, 0.f, 0.f, 0.f};

    for (int t2 = 0; t2 < 2; t2++) {
        int k0 = t2 * 128;
#pragma unroll
        for (int h = 0; h < 2; h++) {     // two 64-k halves, back-to-back issue
#pragma unroll
            for (int q = 0; q < 2; q++)
                gl_lds16(asrc[q] + k0 + h * 64, &As[h][(q * 4 + wave) * 512]);
#pragma unroll
            for (int q = 0; q < 4; q++)
                gl_lds16(bsrc[q] + k0 + h * 64, &Bs[h][(q * 4 + wave) * 512]);
        }
        __syncthreads();                  // single drain covers 128 k
#pragma unroll
        for (int h = 0; h < 2; h++) {
            const ushort_t* Ac = As[h];
            const ushort_t* Bc = Bs[h];
#pragma unroll
            for (int kk = 0; kk < 2; kk++) {
                bf16x8 af[2], bfg[4];
#pragma unroll
                for (int i = 0; i < 2; i++) {
                    int row = wm * 32 + i * 16 + col;
                    af[i] = *(const bf16x8*)&Ac[row * 64 + ((kk * 4 + quad) ^ (row & 7)) * 8];
                }
#pragma unroll
                for (int j = 0; j < 4; j++) {
                    int row = wn * 64 + j * 16 + col;
                    bfg[j] = *(const bf16x8*)&Bc[row * 64 + ((kk * 4 + quad) ^ (row & 7)) * 8];
                }
#pragma unroll
                for (int i = 0; i < 2; i++)
#pragma unroll
                    for (int j = 0; j < 4; j++)
                        acc[i][j] = __builtin_amdgcn_mfma_f32_16x16x32_bf16(bfg[j], af[i], acc[i][j], 0, 0, 0);
            }
        }
        __syncthreads();
    }

    // epilogue: n_sec = nh*128 + wn*64 + j*16 + quad*4 + r; m = m0+wm*32+i*16+col
    ushort_t* dst = (sec == 0) ? Qb : (sec == 1) ? Kb : Vb;
    float bsc = (sec == 0) ? ALPHA : 1.f;    // Q bias folded with softmax scale
    int nb0 = nh * 128 + wn * 64 + quad * 4;
#pragma unroll
    for (int j = 0; j < 4; j++) {
        float4 bv = *(const float4*)(bias + sec * 256 + nb0 + j * 16);
        bv.x *= bsc; bv.y *= bsc; bv.z *= bsc; bv.w *= bsc;
#pragma unroll
        for (int i = 0; i < 2; i++) {
            int m = m0 + wm * 32 + i * 16 + col;
            uint2 st;
            st.x = pk_rne(acc[i][j][0] + bv.x, acc[i][j][1] + bv.y);
            st.y = pk_rne(acc[i][j][2] + bv.z, acc[i][j][3] + bv.w);
            *(uint2*)(dst + (size_t)m * 256 + nb0 + j * 16) = st;
        }
    }
}

// ---------------- Kernel 3: MFMA attention per (pixel p, head h) ----------------
// 512 threads (8 waves, 4 q-tiles each), single-shot staging of all 512 keys.
// Ks[key][32] with chunk XOR (quad ^ (key>>3)&3): conflict-free b128 reads.
// Vt[vc][512] transposed; swizzle swz(vc) = (vc&7) ^ ((vc>>3)<<1) on write AND read.
// Q pre-scaled by ALPHA (log2 domain) -> softmax numerator is bare v_exp_f32.
// qsum via ones-operand MFMA (accS) — row-sum on the matrix pipe (r10).
__global__ __launch_bounds__(512, 4) void k_attn(const ushort_t* __restrict__ Qb,
                                                 const ushort_t* __restrict__ Kb,
                                                 const ushort_t* __restrict__ Vb,
                                                 ushort_t* __restrict__ AO) {
    __shared__ __align__(16) ushort_t Ks[512 * 32];   // 32 KiB
    __shared__ __align__(16) ushort_t Vt[32 * 512];   // 32 KiB
    int p = blockIdx.x >> 3, h = blockIdx.x & 7;
    int tid = threadIdx.x;
    int lane = tid & 63, wave = tid >> 6;             // wave 0..7
    int col = lane & 15, quad = lane >> 4;

    // K staging: unit = (key, oct); bf16x8 -> swizzled chunk
#pragma unroll
    for (int it = 0; it < 4; it++) {
        int u = it * 512 + tid;
        int key = u >> 2, oct = u & 3;
        size_t grow = ((size_t)(key * 64 + p)) * 256 + h * 32 + oct * 8;
        int ck = oct ^ ((key >> 3) & 3);
        *(bf16x8*)&Ks[key * 32 + ck * 8] = *(const bf16x8*)(Kb + grow);
    }
    // V staging: unit = (key-pair, oct); pack 2 keys/chan -> ds_write_b32
#pragma unroll
    for (int it = 0; it < 2; it++) {
        int u = it * 512 + tid;
        int kp = u >> 2, oct = u & 3;
        int k0 = kp * 2;
        size_t g0 = ((size_t)(k0 * 64 + p)) * 256 + h * 32 + oct * 8;
        bf16x8 v0 = *(const bf16x8*)(Vb + g0);
        bf16x8 v1 = *(const bf16x8*)(Vb + g0 + 16384);   // key+1 row
        int kc = kp >> 2;                                // key>>3
#pragma unroll
        for (int j = 0; j < 8; j++) {
            int vc = oct * 8 + j;
            int kcs = kc ^ (vc & 7) ^ ((vc >> 3) << 1);
            uint_t pkv = (uint_t)(ushort_t)v0[j] | ((uint_t)(ushort_t)v1[j] << 16);
            *(uint_t*)&Vt[vc * 512 + kcs * 8 + (k0 & 7)] = pkv;
        }
    }

    // Q fragments (independent global loads, overlap with staging)
    bf16x8 qfrag[4];
#pragma unroll
    for (int i = 0; i < 4; i++) {
        int qt = wave * 4 + i;
        qfrag[i] = *(const bf16x8*)(Qb + ((size_t)((qt * 16 + col) * 64 + p)) * 256 + h * 32 + quad * 8);
    }

    f32x4 O0[4], O1[4], accS[4];
#pragma unroll
    for (int i = 0; i < 4; i++) {
        O0[i] = (f32x4){0.f, 0.f, 0.f, 0.f};
        O1[i] = (f32x4){0.f, 0.f, 0.f, 0.f};
        accS[i] = (f32x4){0.f, 0.f, 0.f, 0.f};
    }
    const f32x4 zero = {0.f, 0.f, 0.f, 0.f};
    const short OB = (short)0x3F80;                  // bf16 1.0
    const bf16x8 ones8 = {OB, OB, OB, OB, OB, OB, OB, OB};
    int R = col >> 2, r4 = lane & 3;
    int krow0 = 8 * R + r4;                  // kf0 row offset; kf1 = +4
    int vc0 = col, vc1 = col + 16;
    int sw0 = (vc0 & 7) ^ ((vc0 >> 3) << 1); // full swizzle, matches write
    int sw1 = (vc1 & 7) ^ ((vc1 >> 3) << 1);

    __syncthreads();

    for (int c = 0; c < 512; c += 32) {
        int row0 = c + krow0;
        int row1 = row0 + 4;
        int ckq = quad ^ ((row0 >> 3) & 3);  // same for row1 (r4<4)
        bf16x8 kf0 = *(const bf16x8*)&Ks[row0 * 32 + ckq * 8];
        bf16x8 kf1 = *(const bf16x8*)&Ks[row1 * 32 + ckq * 8];
        int kc = (c >> 3) + quad;
        bf16x8 vf0 = *(const bf16x8*)&Vt[vc0 * 512 + ((kc ^ sw0) * 8)];
        bf16x8 vf1 = *(const bf16x8*)&Vt[vc1 * 512 + ((kc ^ sw1) * 8)];
#pragma unroll
        for (int i = 0; i < 4; i++) {
            __builtin_amdgcn_s_setprio(1);
            f32x4 s0 = __builtin_amdgcn_mfma_f32_16x16x32_bf16(kf0, qfrag[i], zero, 0, 0, 0);
            f32x4 s1 = __builtin_amdgcn_mfma_f32_16x16x32_bf16(kf1, qfrag[i], zero, 0, 0, 0);
            __builtin_amdgcn_s_setprio(0);
            float p0[4], p1[4];
#pragma unroll
            for (int r = 0; r < 4; r++) {
                p0[r] = __builtin_amdgcn_exp2f(s0[r]);
                p1[r] = __builtin_amdgcn_exp2f(s1[r]);
            }
            union { uint_t u[4]; bf16x8 v; } pb;
            pb.u[0] = pk2(p0[0], p0[1]);
            pb.u[1] = pk2(p0[2], p0[3]);
            pb.u[2] = pk2(p1[0], p1[1]);
            pb.u[3] = pk2(p1[2], p1[3]);
            __builtin_amdgcn_s_setprio(1);
            O0[i] = __builtin_amdgcn_mfma_f32_16x16x32_bf16(vf0, pb.v, O0[i], 0, 0, 0);
            O1[i] = __builtin_amdgcn_mfma_f32_16x16x32_bf16(vf1, pb.v, O1[i], 0, 0, 0);
            accS[i] = __builtin_amdgcn_mfma_f32_16x16x32_bf16(ones8, pb.v, accS[i], 0, 0, 0);
            __builtin_amdgcn_s_setprio(0);
        }
    }

#pragma unroll
    for (int i = 0; i < 4; i++) {
        float inv = 1.f / accS[i][0];        // full 512-key sum, uniform in quad
        int qt = wave * 4 + i;
        ushort_t* dst = AO + ((size_t)((qt * 16 + col) * 64 + p)) * 256 + h * 32;
        uint2 st0, st1;
        st0.x = pk_rne(O0[i][0] * inv, O0[i][1] * inv);
        st0.y = pk_rne(O0[i][2] * inv, O0[i][3] * inv);
        st1.x = pk_rne(O1[i][0] * inv, O1[i][1] * inv);
        st1.y = pk_rne(O1[i][2] * inv, O1[i][3] * inv);
        *(uint2*)(dst + quad * 4) = st0;
        *(uint2*)(dst + 16 + quad * 4) = st1;
    }
}

// --- Kernel 4: out-proj GEMM + residual + scatter, m97-structure -------------
__global__ __launch_bounds__(256, 4) void k_gemm_out3(const ushort_t* __restrict__ A,
                                                      const ushort_t* __restrict__ Bw,
                                                      const float* __restrict__ bias,
                                                      const ushort_t* __restrict__ G,
                                                      const float* __restrict__ x,
                                                      const float* __restrict__ ca,
                                                      float* __restrict__ out) {
    __shared__ __align__(16) ushort_t As[4096];    // 8 KiB: 64 rows x 64 k
    __shared__ __align__(16) ushort_t Bs[8192];    // 16 KiB: 128 rows x 64 k
    int tid = threadIdx.x;
    int lane = tid & 63, wave = tid >> 6;
    int wm = wave >> 1, wn = wave & 1;             // wave tile: 32m x 64n
    int col = lane & 15, quad = lane >> 4;
    int orig = blockIdx.x;                // 0..1023
    int xcd = orig & 7;
    int i128 = orig >> 3;                 // 0..127
    int mi = i128 >> 1;                   // 0..63 local m-panel (token)
    int ns = i128 & 1;
    int m0 = (xcd * 64 + mi) * 64;        // token base row
    int n0 = ns * 128;

    int cbase = wave * 64 + lane;
    const ushort_t* asrc[2];
    const ushort_t* bsrc[4];
#pragma unroll
    for (int q = 0; q < 2; q++) {
        int c = q * 256 + cbase;          // A chunk 0..511
        int row = c >> 3;                 // 0..63
        int kp = (c & 7) ^ (row & 7);
        asrc[q] = A + (size_t)(m0 + row) * 256 + kp * 8;
    }
#pragma unroll
    for (int q = 0; q < 4; q++) {
        int c = q * 256 + cbase;          // B chunk 0..1023
        int row = c >> 3;                 // 0..127
        int kp = (c & 7) ^ (row & 7);
        bsrc[q] = Bw + (size_t)(n0 + row) * 256 + kp * 8;
    }

    f32x4 acc[2][4];
#pragma unroll
    for (int i = 0; i < 2; i++)
#pragma unroll
        for (int j = 0; j < 4; j++) acc[i][j] = (f32x4){0.f, 0.f, 0.f, 0.f};

    for (int t = 0; t < 4; t++) {
        int k0 = t * 64;
#pragma unroll
        for (int q = 0; q < 2; q++) gl_lds16(asrc[q] + k0, &As[(q * 4 + wave) * 512]);
#pragma unroll
        for (int q = 0; q < 4; q++) gl_lds16(bsrc[q] + k0, &Bs[(q * 4 + wave) * 512]);
        __syncthreads();
#pragma unroll
        for (int kk = 0; kk < 2; kk++) {
            bf16x8 af[2], bfg[4];
#pragma unroll
            for (int i = 0; i < 2; i++) {
                int row = wm * 32 + i * 16 + col;
                af[i] = *(const bf16x8*)&As[row * 64 + ((kk * 4 + quad) ^ (row & 7)) * 8];
            }
#pragma unroll
            for (int j = 0; j < 4; j++) {
                int row = wn * 64 + j * 16 + col;
                bfg[j] = *(const bf16x8*)&Bs[row * 64 + ((kk * 4 + quad) ^ (row & 7)) * 8];
            }
#pragma unroll
            for (int i = 0; i < 2; i++)
#pragma unroll
                for (int j = 0; j < 4; j++)
                    acc[i][j] = __builtin_amdgcn_mfma_f32_16x16x32_bf16(bfg[j], af[i], acc[i][j], 0, 0, 0);
        }
        __syncthreads();
    }

    // epilogue: block = one token lw = m0>>6; px = wm*32 + i*16 + col
    int lw = m0 >> 6;
    int b = lw & 7, w_idx = lw >> 3;
    int hw = w_idx >> 3, ww = w_idx & 7;
    if (G != nullptr) {
#pragma unroll
        for (int j = 0; j < 4; j++) {
            int nbase = n0 + wn * 64 + j * 16 + quad * 4;
            float4 bv = *(const float4*)(bias + nbase);
#pragma unroll
            for (int i = 0; i < 2; i++) {
                int px = wm * 32 + i * 16 + col;
                // residual = x*ca at NORMAL spatial (h=w_idx, w=px)
                int mres = ((hw * 8 + (px >> 3)) * 8 + b) * 64 + ww * 8 + (px & 7);
                uint2 gv = *(const uint2*)(G + (size_t)mres * 256 + nbase);
                float g0 = bfh(gv.x & 0xffffu), g1 = bfh(gv.x >> 16);
                float g2 = bfh(gv.y & 0xffffu), g3 = bfh(gv.y >> 16);
                size_t ob = (((size_t)b * 256 + nbase) * 64 + w_idx) * 64 + px;
                out[ob]            = acc[i][j][0] + bv.x + g0;
                out[ob + 4096]     = acc[i][j][1] + bv.y + g1;
                out[ob + 2 * 4096] = acc[i][j][2] + bv.z + g2;
                out[ob + 3 * 4096] = acc[i][j][3] + bv.w + g3;
            }
        }
    } else {
#pragma unroll
        for (int j = 0; j < 4; j++) {
            int nbase = n0 + wn * 64 + j * 16 + quad * 4;
            float4 bv = *(const float4*)(bias + nbase);
            float4 cv = *(const float4*)(ca + b * 256 + nbase);
#pragma unroll
            for (int i = 0; i < 2; i++) {
                int px = wm * 32 + i * 16 + col;
#pragma unroll
                for (int r = 0; r < 4; r++) {
                    int n = nbase + r;
                    float bias_r = (r == 0) ? bv.x : (r == 1) ? bv.y : (r == 2) ? bv.z : bv.w;
                    float ca_r = (r == 0) ? cv.x : (r == 1) ? cv.y : (r == 2) ? cv.z : cv.w;
                    size_t oi = (((size_t)b * 256 + n) * 64 + w_idx) * 64 + px;
                    out[oi] = acc[i][j][r] + bias_r + x[oi] * ca_r;
                }
            }
        }
    }
}

extern "C" void kernel_launch(void* const* d_in, const int* in_sizes, int n_in,
                              void* d_out, int out_size, void* d_ws, size_t ws_size,
                              hipStream_t stream) {
    const float* x     = (const float*)d_in[0];
    const float* ca_w1 = (const float*)d_in[1];
    const float* ca_b1 = (const float*)d_in[2];
    const float* ca_w2 = (const float*)d_in[3];
    const float* ca_b2 = (const float*)d_in[4];
    const float* ipw   = (const float*)d_in[5];
    const float* ipb   = (const float*)d_in[6];
    const float* opw   = (const float*)d_in[7];
    const float* opb   = (const float*)d_in[8];
    float* out = (float*)d_out;

    char* ws = (char*)d_ws;
    const size_t MB16 = 16777216ull;
    ushort_t* Qb = (ushort_t*)(ws + 0);          // 16 MiB; AO aliases this
    ushort_t* Kb = (ushort_t*)(ws + MB16);       // 16 MiB
    ushort_t* Vb = (ushort_t*)(ws + 2 * MB16);   // 16 MiB
    float* pooled = (float*)(ws + 3 * MB16);     // 8 KiB
    float* ca     = (float*)(ws + 3 * MB16 + 8192);

    // big_ws layout: Wob @ +16 KiB, Wqb @ +160 KiB, Ab @ 49 MiB (16 MiB).
    const size_t WOB_OFF = 3 * MB16 + 16384;
    const size_t WQB_OFF = 3 * MB16 + 163840;
    const size_t AB_OFF  = 3 * MB16 + 1048576;
    bool big_ws = (ws_size >= AB_OFF + MB16);

    ushort_t* Wob, *Wqb, *Ab;
    const ushort_t* G;
    if (big_ws) {
        Wob = (ushort_t*)(ws + WOB_OFF);
        Wqb = (ushort_t*)(ws + WQB_OFF);
        Ab  = (ushort_t*)(ws + AB_OFF);
        G   = Ab;                                 // residual from gated bf16
    } else {
        // fallback: d_out as scratch (as round 6); residual from x*ca
        Ab  = (ushort_t*)d_out;
        Wqb = (ushort_t*)((char*)d_out + MB16);
        Wob = Vb;                                 // late cvt into Vb post-attn
        G   = nullptr;
    }

    k_pre<<<big_ws ? 2176 : 2144, 256, 0, stream>>>(x, pooled, ipw, Wqb, opw, Wob);
    if (!big_ws) k_se<<<1, 256, 0, stream>>>(pooled, ca_w1, ca_b1, ca_w2, ca_b2, ca);
    k_gate<<<512, 256, 0, stream>>>(x, pooled, ca_w1, ca_b1, ca_w2, ca_b2, Ab);
    k_gemm_qkv4<<<3072, 256, 0, stream>>>(Ab, Wqb, ipb, Qb, Kb, Vb);
    k_attn<<<512, 512, 0, stream>>>(Qb, Kb, Vb, Qb /* AO aliases Q */);
    if (!big_ws) k_cvt<<<32, 256, 0, stream>>>(opw, Vb, 8192, 0, 1.f);
    k_gemm_out3<<<1024, 256, 0, stream>>>(Qb, Wob, opb, G, x, ca, out);
}